// Round 8
// baseline (2920.014 us; speedup 1.0000x reference)
//
#include <hip/hip_runtime.h>
#include <math.h>

#define BB 16
#define KK 4
#define VV 32000
#define DD 512
#define LL 32
#define EOS_ID 2
#define NEGINF 1.0e7f
#define ALPHA_C 0.6f
#define NROW (BB * KK)        // 64
#define NBLK 500              // k_logits blocks, 64 cols each
#define NSLOT 6
#define SPLIT_S 2048.0f

typedef _Float16 f16x8 __attribute__((ext_vector_type(8)));
typedef float f32x4 __attribute__((ext_vector_type(4)));

#define GLOAD_LDS16(gp, lp) \
    __builtin_amdgcn_global_load_lds( \
        (const __attribute__((address_space(1))) void*)(gp), \
        (__attribute__((address_space(3))) void*)(lp), 16, 0, 0)

// branchless stable top-8 insert (strict >: earlier/lower index wins ties).
#define INS8(v, idx, lv, li)                                          \
    if ((v) > lv[7]) {                                                \
        bool c_[8];                                                   \
        _Pragma("unroll")                                             \
        for (int j_ = 0; j_ < 8; j_++) c_[j_] = (v) > lv[j_];         \
        _Pragma("unroll")                                             \
        for (int j_ = 7; j_ >= 1; j_--) {                             \
            lv[j_] = c_[j_] ? (c_[j_ - 1] ? lv[j_ - 1] : (v)) : lv[j_];   \
            li[j_] = c_[j_] ? (c_[j_ - 1] ? li[j_ - 1] : (idx)) : li[j_]; \
        }                                                             \
        if (c_[0]) { lv[0] = (v); li[0] = (idx); }                    \
    }

// rank-based stable merge of two sorted-descending top-8 lists.
// A lives in LDS (in-place result); B is in registers (constant-indexed).
// All private arrays constant-indexed (no scratch); runtime ranks index LDS only.
// Comparator: X before Y iff valX>valY || (valX==valY && idxX<idxY). Distinct idx
// => unique ranks => result independent of merge order (== jax.lax.top_k order).
__device__ inline void rank_merge(float* Av, int* Ai,
                                  const float bv[8], const int bi[8]) {
    float av[8]; int ai[8];
    #pragma unroll
    for (int i = 0; i < 8; i++) { av[i] = Av[i]; ai[i] = Ai[i]; }
    int ra[8], rb[8];
    #pragma unroll
    for (int i = 0; i < 8; i++) { ra[i] = i; rb[i] = i; }
    #pragma unroll
    for (int i = 0; i < 8; i++)
        #pragma unroll
        for (int j = 0; j < 8; j++) {
            bool bBeforeA = (bv[j] > av[i]) || (bv[j] == av[i] && bi[j] < ai[i]);
            ra[i] += bBeforeA ? 1 : 0;
            rb[j] += bBeforeA ? 0 : 1;
        }
    #pragma unroll
    for (int i = 0; i < 8; i++) if (ra[i] < 8) { Av[ra[i]] = av[i]; Ai[ra[i]] = ai[i]; }
    #pragma unroll
    for (int j = 0; j < 8; j++) if (rb[j] < 8) { Av[rb[j]] = bv[j]; Ai[rb[j]] = bi[j]; }
}

// pack h value (global row r, depth d) into MFMA A-fragment order (fp16 hi/lo split)
__device__ inline void pack_h(int r, int d, float v,
                              _Float16* __restrict__ hfrag_hi,
                              _Float16* __restrict__ hfrag_lo) {
    _Float16 hi = (_Float16)v;
    _Float16 lo = (_Float16)((v - (float)hi) * SPLIT_S);
    int rg = r >> 4;
    int ks = d >> 5;
    int lane = (r & 15) + 16 * ((d >> 3) & 3);
    int e = d & 7;
    int off = (((rg * 16 + ks) * 64) + lane) * 8 + e;
    hfrag_hi[off] = hi;
    hfrag_lo[off] = lo;
}

// ---------------- init: sequences / scores ----------------
__global__ void k_init(const int* __restrict__ initial_ids,
                       int* alive_seq, float* alive_lp,
                       int* fin_seq, float* fin_sc, int* fin_fl) {
    int tid = blockIdx.x * blockDim.x + threadIdx.x;
    int nthreads = gridDim.x * blockDim.x;
    const int SEQ = NROW * (LL + 1);
    for (int idx = tid; idx < SEQ; idx += nthreads) {
        int pos = idx % (LL + 1);
        int b = (idx / (LL + 1)) / KK;
        alive_seq[idx] = (pos == 0) ? initial_ids[b] : 0;
        fin_seq[idx] = 0;
    }
    for (int idx = tid; idx < NROW; idx += nthreads) {
        int k = idx % KK;
        alive_lp[idx] = (k == 0) ? 0.0f : -NEGINF;
        fin_sc[idx] = -NEGINF;
        fin_fl[idx] = 0;
    }
}

// ---------------- one-time: proj -> fp16 hi/lo B-fragments ----------------
__global__ __launch_bounds__(256) void k_bconv(const float* __restrict__ proj,
                                               _Float16* __restrict__ bfrag_hi,
                                               _Float16* __restrict__ bfrag_lo) {
    int ct = blockIdx.x;
    int t = threadIdx.x;
    int w = t >> 6, l = t & 63;
    int col = ct * 16 + (l & 15);
    int kg = l >> 4;
    for (int ks = w; ks < 16; ks += 4) {
        int k0 = ks * 32 + kg * 8;
        f16x8 hi, lo;
        #pragma unroll
        for (int j = 0; j < 8; j++) {
            float v = proj[(size_t)(k0 + j) * VV + col];
            _Float16 h = (_Float16)v;
            hi[j] = h;
            lo[j] = (_Float16)((v - (float)h) * SPLIT_S);
        }
        size_t off = (size_t)(ct * 16 + ks) * 64 + l;
        reinterpret_cast<f16x8*>(bfrag_hi)[off] = hi;
        reinterpret_cast<f16x8*>(bfrag_lo)[off] = lo;
    }
}

// ---------------- initial h ----------------
__global__ void k_hinit(const int* __restrict__ initial_ids,
                        const float* __restrict__ init_h,
                        const float* __restrict__ embed,
                        float* __restrict__ h_buf,
                        _Float16* __restrict__ hfrag_hi,
                        _Float16* __restrict__ hfrag_lo) {
    int row = blockIdx.x;
    int b = row >> 2;
    int t = threadIdx.x;
    int tok = initial_ids[b];
    for (int d = t; d < DD; d += 256) {
        float v = tanhf(init_h[b * DD + d] + embed[(size_t)tok * DD + d]);
        h_buf[row * DD + d] = v;
        pack_h(row, d, v, hfrag_hi, hfrag_lo);
    }
}

// ---------------- logits via MFMA fp16x2 split + fused per-block row-reduce ---------
// grid 500, block 256 (4 waves). Block: all 64 rows x 64 cols (4 col-tiles).
__global__ __launch_bounds__(256) void k_logits(
        const _Float16* __restrict__ bfrag_hi,
        const _Float16* __restrict__ bfrag_lo,
        const _Float16* __restrict__ hfrag_hi,
        const _Float16* __restrict__ hfrag_lo,
        float* __restrict__ ptv, int* __restrict__ pti,
        float* __restrict__ pm, float* __restrict__ ps) {
    int t = threadIdx.x;
    int w = t >> 6, l = t & 63;
    int ct0 = blockIdx.x * 4;
    int c0 = ct0 * 16;
    int colr = l & 15;
    int kg = l >> 4;
    int lq = l * 8;

    __shared__ _Float16 Bs[NSLOT][4][2][512];   // 48 KB; reused by epilogue

    f16x8 ah[16], al[16];
    #pragma unroll
    for (int ks = 0; ks < 16; ks++) {
        ah[ks] = *reinterpret_cast<const f16x8*>(hfrag_hi + ((w * 16 + ks) * 64 + l) * 8);
        al[ks] = *reinterpret_cast<const f16x8*>(hfrag_lo + ((w * 16 + ks) * 64 + l) * 8);
    }
    asm volatile("s_waitcnt vmcnt(0)" ::: "memory");
    __builtin_amdgcn_sched_barrier(0);

    f32x4 acc1[4], acc2[4];
    #pragma unroll
    for (int c2 = 0; c2 < 4; c2++) {
        acc1[c2] = (f32x4){0.f, 0.f, 0.f, 0.f};
        acc2[c2] = (f32x4){0.f, 0.f, 0.f, 0.f};
    }

    auto stage = [&](int s) {
        int slot = s % NSLOT;
        const _Float16* gh = bfrag_hi + (((size_t)(ct0 + w) * 16 + s) * 64 + l) * 8;
        const _Float16* gl = bfrag_lo + (((size_t)(ct0 + w) * 16 + s) * 64 + l) * 8;
        GLOAD_LDS16(gh, &Bs[slot][w][0][0]);
        GLOAD_LDS16(gl, &Bs[slot][w][1][0]);
    };

    stage(0); stage(1); stage(2); stage(3); stage(4); stage(5);

#define ITER(ks, NWAIT)                                                         \
    {                                                                           \
        asm volatile("s_waitcnt vmcnt(" #NWAIT ")" ::: "memory");               \
        __builtin_amdgcn_s_barrier();                                           \
        f16x8 bq[4][2];                                                         \
        _Pragma("unroll")                                                       \
        for (int c2 = 0; c2 < 4; c2++) {                                        \
            bq[c2][0] = *reinterpret_cast<const f16x8*>(&Bs[(ks) % NSLOT][c2][0][lq]); \
            bq[c2][1] = *reinterpret_cast<const f16x8*>(&Bs[(ks) % NSLOT][c2][1][lq]); \
        }                                                                       \
        asm volatile("s_waitcnt lgkmcnt(0)" ::: "memory");                      \
        __builtin_amdgcn_s_barrier();                                           \
        if ((ks) + NSLOT < 16) stage((ks) + NSLOT);                             \
        _Pragma("unroll")                                                       \
        for (int c2 = 0; c2 < 4; c2++) {                                        \
            acc1[c2] = __builtin_amdgcn_mfma_f32_16x16x32_f16(ah[(ks)], bq[c2][0], acc1[c2], 0, 0, 0); \
            acc2[c2] = __builtin_amdgcn_mfma_f32_16x16x32_f16(ah[(ks)], bq[c2][1], acc2[c2], 0, 0, 0); \
            acc2[c2] = __builtin_amdgcn_mfma_f32_16x16x32_f16(al[(ks)], bq[c2][0], acc2[c2], 0, 0, 0); \
        }                                                                       \
    }

    ITER(0, 10)  ITER(1, 10)  ITER(2, 10)  ITER(3, 10)
    ITER(4, 10)  ITER(5, 10)  ITER(6, 10)  ITER(7, 10)
    ITER(8, 10)  ITER(9, 10)  ITER(10, 10) ITER(11, 8)
    ITER(12, 6)  ITER(13, 4)  ITER(14, 2)  ITER(15, 0)
#undef ITER

    // ---- fused row-reduce epilogue (Bs is dead; reuse as scratch pool) ----
    char* pool = (char*)&Bs[0][0][0][0];
    float* Cs  = (float*)pool;               // [64][65] = 16640 B
    float* sv  = (float*)(pool + 16640);     // [256][8]
    int*   si  = (int*)  (pool + 24832);     // [256][8]
    float* smx = (float*)(pool + 33024);     // [256]
    float* ssm = (float*)(pool + 34048);     // [256]

    #pragma unroll
    for (int c2 = 0; c2 < 4; c2++)
        #pragma unroll
        for (int j = 0; j < 4; j++)
            Cs[(w * 16 + kg * 4 + j) * 65 + c2 * 16 + colr] =
                acc1[c2][j] + acc2[c2][j] * (1.0f / SPLIT_S);
    __syncthreads();

    int row = t >> 2, cg = t & 3;
    float lv[8]; int li[8];
    #pragma unroll
    for (int j = 0; j < 8; j++) { lv[j] = -INFINITY; li[j] = 0x7fffffff; }
    float m = -INFINITY, s = 0.0f;
    #pragma unroll
    for (int cc = 0; cc < 16; cc++) {
        float v = Cs[row * 65 + cg * 16 + cc];
        int idx = c0 + cg * 16 + cc;
        float M = fmaxf(m, v);
        s = s * expf(m - M) + expf(v - M);
        m = M;
        INS8(v, idx, lv, li)
    }
    #pragma unroll
    for (int j = 0; j < 8; j++) { sv[t * 8 + j] = lv[j]; si[t * 8 + j] = li[j]; }
    smx[t] = m; ssm[t] = s;
    __syncthreads();
    for (int st = 2; st > 0; st >>= 1) {
        if ((t & 3) < st) {
            float rv[8]; int ri[8];
            int pa = 0, pb = 0;
            #pragma unroll
            for (int j = 0; j < 8; j++) {
                bool aok = pa < 8, bok = pb < 8;
                float va = sv[t * 8 + (aok ? pa : 7)], vb = sv[(t + st) * 8 + (bok ? pb : 7)];
                int   ia = si[t * 8 + (aok ? pa : 7)], ib = si[(t + st) * 8 + (bok ? pb : 7)];
                bool takeA = !bok || (aok && ((va > vb) || (va == vb && ia <= ib)));
                if (takeA) { rv[j] = va; ri[j] = ia; pa++; }
                else       { rv[j] = vb; ri[j] = ib; pb++; }
            }
            #pragma unroll
            for (int j = 0; j < 8; j++) { sv[t * 8 + j] = rv[j]; si[t * 8 + j] = ri[j]; }
            float ma = smx[t], mb = smx[t + st];
            float M = fmaxf(ma, mb);
            ssm[t] = ssm[t] * expf(ma - M) + ssm[t + st] * expf(mb - M);
            smx[t] = M;
        }
        __syncthreads();
    }
    if ((t & 3) == 0) {
        size_t base = ((size_t)row * NBLK + blockIdx.x) * 8;
        #pragma unroll
        for (int j = 0; j < 8; j++) { ptv[base + j] = sv[t * 8 + j]; pti[base + j] = si[t * 8 + j]; }
        pm[(size_t)row * NBLK + blockIdx.x] = smx[t];
        ps[(size_t)row * NBLK + blockIdx.x] = ssm[t];
    }
}

// ---------------- beam update: fused merge (LDS lists + rank-merge) + selection ----
// grid BB, block 512 (__launch_bounds__(512,1): no register cap -> no scratch spill).
// Merge: 128 lanes/row, per-lane list in LDS, rank-based 8x8 merges, 7-level tree.
__global__ __launch_bounds__(512, 1) void k_update(
        const float* __restrict__ embed,
        float* h_buf, int* alive_seq, float* alive_lp,
        int* fin_seq, float* fin_sc, int* fin_fl,
        const float* __restrict__ ptv, const int* __restrict__ pti,
        const float* __restrict__ pm, const float* __restrict__ ps,
        _Float16* __restrict__ hfrag_hi, _Float16* __restrict__ hfrag_lo,
        int step) {
    int b = blockIdx.x;
    int t = threadIdx.x;
    int rloc = t >> 7, lane = t & 127;
    int grow = b * KK + rloc;

    __shared__ float h_old[KK][DD];                       // 8 KB
    __shared__ int old_aseq[KK][LL + 1], old_fseq[KK][LL + 1];
    __shared__ float msv[KK][128][8];                     // 16 KB
    __shared__ int   msi[KK][128][8];                     // 16 KB
    __shared__ float msm[KK][128], mss[KK][128];          // 4 KB
    __shared__ float lse_s[KK], alp_s[KK];
    __shared__ float clp[32]; __shared__ int cidx[32];
    __shared__ float c_lp[8];  __shared__ int c_beam[8], c_id[8], c_fl[8];
    __shared__ float asc_s[8], comb_s[12]; __shared__ int combfl_s[12];
    __shared__ int sel_alive[KK], sel_fin[KK];
    __shared__ float n_alp[KK], n_fsc[KK]; __shared__ int n_ffl[KK];

    // stage old state (overlaps with merge loads)
    for (int idx = t; idx < KK * (LL + 1); idx += 512) {
        old_aseq[idx / (LL + 1)][idx % (LL + 1)] = alive_seq[b * KK * (LL + 1) + idx];
        old_fseq[idx / (LL + 1)][idx % (LL + 1)] = fin_seq[b * KK * (LL + 1) + idx];
    }
    for (int idx = t; idx < KK * DD; idx += 512)
        h_old[idx >> 9][idx & (DD - 1)] = h_buf[b * KK * DD + idx];

    // ---- per-lane: init list from partial `lane`, rank-merge in lane+128,256,384 ----
    {
        const float* pv0 = ptv + ((size_t)grow * NBLK + lane) * 8;
        const int*   pi0 = pti + ((size_t)grow * NBLK + lane) * 8;
        #pragma unroll
        for (int j = 0; j < 8; j++) { msv[rloc][lane][j] = pv0[j]; msi[rloc][lane][j] = pi0[j]; }
    }
    float m = pm[(size_t)grow * NBLK + lane];
    float s = ps[(size_t)grow * NBLK + lane];
    for (int p = lane + 128; p < NBLK; p += 128) {
        const float* bvp = ptv + ((size_t)grow * NBLK + p) * 8;
        const int*   bip = pti + ((size_t)grow * NBLK + p) * 8;
        float bv[8]; int bi[8];
        #pragma unroll
        for (int j = 0; j < 8; j++) { bv[j] = bvp[j]; bi[j] = bip[j]; }
        rank_merge(&msv[rloc][lane][0], &msi[rloc][lane][0], bv, bi);
        float mb = pm[(size_t)grow * NBLK + p], sb = ps[(size_t)grow * NBLK + p];
        float M = fmaxf(m, mb);
        s = s * expf(m - M) + sb * expf(mb - M);
        m = M;
    }
    msm[rloc][lane] = m; mss[rloc][lane] = s;
    __syncthreads();
    // ---- tree 128 -> 1 per row ----
    for (int st = 64; st > 0; st >>= 1) {
        if (lane < st) {
            float bv[8]; int bi[8];
            #pragma unroll
            for (int j = 0; j < 8; j++) { bv[j] = msv[rloc][lane + st][j]; bi[j] = msi[rloc][lane + st][j]; }
            rank_merge(&msv[rloc][lane][0], &msi[rloc][lane][0], bv, bi);
            float ma = msm[rloc][lane], mb = msm[rloc][lane + st];
            float M = fmaxf(ma, mb);
            mss[rloc][lane] = mss[rloc][lane] * expf(ma - M) + mss[rloc][lane + st] * expf(mb - M);
            msm[rloc][lane] = M;
        }
        __syncthreads();
    }
    if (t < KK) {
        lse_s[t] = msm[t][0] + logf(mss[t][0]);
        alp_s[t] = alive_lp[b * KK + t];
    }
    __syncthreads();

    // 32 candidates = 4 rows x 8. lp = logit - lse + alive_lp.
    if (t < 32) {
        int row = t >> 3;
        clp[t] = msv[row][0][t & 7] - lse_s[row] + alp_s[row];
        cidx[t] = msi[row][0][t & 7];
    }
    __syncthreads();
    if (t < 32) {   // stable rank (tie key = row*V + token) -> top-8
        int row = t >> 3;
        float mylp = clp[t];
        int mykey = row * VV + cidx[t];
        int cnt = 0;
        #pragma unroll
        for (int j = 0; j < 32; j++) {
            int kj = (j >> 3) * VV + cidx[j];
            cnt += (clp[j] > mylp) || (clp[j] == mylp && kj < mykey);
        }
        if (cnt < 8) {
            c_lp[cnt] = mylp; c_beam[cnt] = row; c_id[cnt] = cidx[t];
            c_fl[cnt] = (cidx[t] == EOS_ID) ? 1 : 0;
        }
    }
    __syncthreads();
    if (t < 8) asc_s[t] = c_lp[t] + (c_fl[t] ? -NEGINF : 0.0f);
    if (t >= 64 && t < 76) {
        int j2 = t - 64;
        if (j2 < 4) { comb_s[j2] = fin_sc[b * KK + j2]; combfl_s[j2] = fin_fl[b * KK + j2]; }
        else {
            int cc = j2 - 4;
            float ln = powf((6.0f + (float)step) / 6.0f, ALPHA_C);
            comb_s[j2] = c_lp[cc] / ln + (c_fl[cc] ? 0.0f : -NEGINF);
            combfl_s[j2] = c_fl[cc];
        }
    }
    __syncthreads();
    if (t < 8) {   // alive: stable top-4 (ties: lower position)
        float a = asc_s[t];
        int cnt = 0;
        #pragma unroll
        for (int j = 0; j < 8; j++) cnt += (asc_s[j] > a) || (asc_s[j] == a && j < t);
        if (cnt < KK) { sel_alive[cnt] = t; n_alp[cnt] = a; }
    }
    if (t >= 64 && t < 76) {  // finished: stable top-4 (ties: lower position)
        int j2 = t - 64;
        float cval = comb_s[j2];
        int cnt = 0;
        #pragma unroll
        for (int j = 0; j < 12; j++) cnt += (comb_s[j] > cval) || (comb_s[j] == cval && j < j2);
        if (cnt < KK) { sel_fin[cnt] = j2; n_fsc[cnt] = cval; n_ffl[cnt] = combfl_s[j2]; }
    }
    __syncthreads();

    for (int idx = t; idx < KK * (LL + 1); idx += 512) {
        int j = idx / (LL + 1), p = idx % (LL + 1);
        int cand = sel_alive[j], bm = c_beam[cand];
        alive_seq[b * KK * (LL + 1) + idx] = (p == step + 1) ? c_id[cand] : old_aseq[bm][p];
        int src = sel_fin[j];
        int fval;
        if (src < 4) fval = old_fseq[src][p];
        else {
            int c2 = src - 4, bm2 = c_beam[c2];
            fval = (p == step + 1) ? c_id[c2] : old_aseq[bm2][p];
        }
        fin_seq[b * KK * (LL + 1) + idx] = fval;
    }
    for (int idx = t; idx < KK * DD; idx += 512) {
        int j = idx >> 9, d = idx & (DD - 1);
        int cand = sel_alive[j], bm = c_beam[cand], tok = c_id[cand];
        float v = tanhf(h_old[bm][d] + embed[(size_t)tok * DD + d]);
        int r = b * KK + j;
        h_buf[(size_t)r * DD + d] = v;
        pack_h(r, d, v, hfrag_hi, hfrag_lo);
    }
    if (t < KK) {
        alive_lp[b * KK + t] = n_alp[t];
        fin_sc[b * KK + t] = n_fsc[t];
        fin_fl[b * KK + t] = n_ffl[t];
    }
}

// ---------------- finalize ----------------
__global__ void k_final(const int* __restrict__ alive_seq, const float* __restrict__ alive_lp,
                        const int* __restrict__ fin_seq, const float* __restrict__ fin_sc,
                        const int* __restrict__ fin_fl, float* __restrict__ out) {
    int b = blockIdx.x;
    int t = threadIdx.x;
    __shared__ int anyf;
    if (t == 0)
        anyf = fin_fl[b * KK] | fin_fl[b * KK + 1] | fin_fl[b * KK + 2] | fin_fl[b * KK + 3];
    __syncthreads();
    for (int idx = t; idx < KK * (LL + 1); idx += blockDim.x) {
        int src = anyf ? fin_seq[b * KK * (LL + 1) + idx] : alive_seq[b * KK * (LL + 1) + idx];
        out[b * KK * (LL + 1) + idx] = (float)src;
    }
    if (t < KK)
        out[BB * KK * (LL + 1) + b * KK + t] = anyf ? fin_sc[b * KK + t] : alive_lp[b * KK + t];
}

extern "C" void kernel_launch(void* const* d_in, const int* in_sizes, int n_in,
                              void* d_out, int out_size, void* d_ws, size_t ws_size,
                              hipStream_t stream) {
    const int* initial_ids = (const int*)d_in[0];
    const float* init_h = (const float*)d_in[1];
    const float* embed = (const float*)d_in[2];
    const float* proj = (const float*)d_in[3];
    float* out = (float*)d_out;

    char* ws = (char*)d_ws;
    size_t off = 0;
    auto alloc = [&](size_t bytes) -> void* {
        off = (off + 255) & ~(size_t)255;
        void* p = ws + off;
        off += bytes;
        return p;
    };
    int* alive_seq    = (int*)alloc((size_t)NROW * (LL + 1) * 4);
    int* fin_seq      = (int*)alloc((size_t)NROW * (LL + 1) * 4);
    float* alive_lp   = (float*)alloc((size_t)NROW * 4);
    float* fin_sc     = (float*)alloc((size_t)NROW * 4);
    int* fin_fl       = (int*)alloc((size_t)NROW * 4);
    float* h_buf      = (float*)alloc((size_t)NROW * DD * 4);
    float* ptv        = (float*)alloc((size_t)NROW * NBLK * 8 * 4);
    int* pti          = (int*)alloc((size_t)NROW * NBLK * 8 * 4);
    float* pm         = (float*)alloc((size_t)NROW * NBLK * 4);
    float* ps         = (float*)alloc((size_t)NROW * NBLK * 4);
    _Float16* hfrag_hi = (_Float16*)alloc((size_t)NROW * DD * 2);
    _Float16* hfrag_lo = (_Float16*)alloc((size_t)NROW * DD * 2);
    _Float16* bfrag_hi = (_Float16*)alloc((size_t)VV * DD * 2);
    _Float16* bfrag_lo = (_Float16*)alloc((size_t)VV * DD * 2);

    k_init<<<16, 256, 0, stream>>>(initial_ids, alive_seq, alive_lp,
                                   fin_seq, fin_sc, fin_fl);
    k_bconv<<<2000, 256, 0, stream>>>(proj, bfrag_hi, bfrag_lo);
    k_hinit<<<NROW, 256, 0, stream>>>(initial_ids, init_h, embed, h_buf,
                                      hfrag_hi, hfrag_lo);
    for (int step = 0; step < LL; step++) {
        k_logits<<<NBLK, 256, 0, stream>>>(bfrag_hi, bfrag_lo, hfrag_hi, hfrag_lo,
                                           ptv, pti, pm, ps);
        k_update<<<BB, 512, 0, stream>>>(embed, h_buf, alive_seq, alive_lp,
                                         fin_seq, fin_sc, fin_fl,
                                         ptv, pti, pm, ps,
                                         hfrag_hi, hfrag_lo, step);
    }
    k_final<<<BB, 64, 0, stream>>>(alive_seq, alive_lp, fin_seq, fin_sc, fin_fl, out);
}

// Round 9
// 1471.487 us; speedup vs baseline: 1.9844x; 1.9844x over previous
//
#include <hip/hip_runtime.h>
#include <math.h>

#define BB 16
#define KK 4
#define VV 32000
#define DD 512
#define LL 32
#define EOS_ID 2
#define NEGINF 1.0e7f
#define ALPHA_C 0.6f
#define NROW (BB * KK)        // 64
#define NBLK 500              // k_logits blocks, 64 cols each
#define NSLOT 6
#define SPLIT_S 2048.0f

typedef _Float16 f16x8 __attribute__((ext_vector_type(8)));
typedef float f32x4 __attribute__((ext_vector_type(4)));

#define GLOAD_LDS16(gp, lp) \
    __builtin_amdgcn_global_load_lds( \
        (const __attribute__((address_space(1))) void*)(gp), \
        (__attribute__((address_space(3))) void*)(lp), 16, 0, 0)

// branchless stable top-8 insert (strict >: earlier/lower index wins ties).
// all private indices compile-time -> stays in VGPRs (rule #20).
#define INS8(v, idx, lv, li)                                          \
    if ((v) > lv[7]) {                                                \
        bool c_[8];                                                   \
        _Pragma("unroll")                                             \
        for (int j_ = 0; j_ < 8; j_++) c_[j_] = (v) > lv[j_];         \
        _Pragma("unroll")                                             \
        for (int j_ = 7; j_ >= 1; j_--) {                             \
            lv[j_] = c_[j_] ? (c_[j_ - 1] ? lv[j_ - 1] : (v)) : lv[j_];   \
            li[j_] = c_[j_] ? (c_[j_ - 1] ? li[j_ - 1] : (idx)) : li[j_]; \
        }                                                             \
        if (c_[0]) { lv[0] = (v); li[0] = (idx); }                    \
    }

// pack h value (global row r, depth d) into MFMA A-fragment order (fp16 hi/lo split)
__device__ inline void pack_h(int r, int d, float v,
                              _Float16* __restrict__ hfrag_hi,
                              _Float16* __restrict__ hfrag_lo) {
    _Float16 hi = (_Float16)v;
    _Float16 lo = (_Float16)((v - (float)hi) * SPLIT_S);
    int rg = r >> 4;
    int ks = d >> 5;
    int lane = (r & 15) + 16 * ((d >> 3) & 3);
    int e = d & 7;
    int off = (((rg * 16 + ks) * 64) + lane) * 8 + e;
    hfrag_hi[off] = hi;
    hfrag_lo[off] = lo;
}

// ---------------- init: sequences / scores ----------------
__global__ void k_init(const int* __restrict__ initial_ids,
                       int* alive_seq, float* alive_lp,
                       int* fin_seq, float* fin_sc, int* fin_fl) {
    int tid = blockIdx.x * blockDim.x + threadIdx.x;
    int nthreads = gridDim.x * blockDim.x;
    const int SEQ = NROW * (LL + 1);
    for (int idx = tid; idx < SEQ; idx += nthreads) {
        int pos = idx % (LL + 1);
        int b = (idx / (LL + 1)) / KK;
        alive_seq[idx] = (pos == 0) ? initial_ids[b] : 0;
        fin_seq[idx] = 0;
    }
    for (int idx = tid; idx < NROW; idx += nthreads) {
        int k = idx % KK;
        alive_lp[idx] = (k == 0) ? 0.0f : -NEGINF;
        fin_sc[idx] = -NEGINF;
        fin_fl[idx] = 0;
    }
}

// ---------------- one-time: proj -> fp16 hi/lo B-fragments ----------------
__global__ __launch_bounds__(256) void k_bconv(const float* __restrict__ proj,
                                               _Float16* __restrict__ bfrag_hi,
                                               _Float16* __restrict__ bfrag_lo) {
    int ct = blockIdx.x;
    int t = threadIdx.x;
    int w = t >> 6, l = t & 63;
    int col = ct * 16 + (l & 15);
    int kg = l >> 4;
    for (int ks = w; ks < 16; ks += 4) {
        int k0 = ks * 32 + kg * 8;
        f16x8 hi, lo;
        #pragma unroll
        for (int j = 0; j < 8; j++) {
            float v = proj[(size_t)(k0 + j) * VV + col];
            _Float16 h = (_Float16)v;
            hi[j] = h;
            lo[j] = (_Float16)((v - (float)h) * SPLIT_S);
        }
        size_t off = (size_t)(ct * 16 + ks) * 64 + l;
        reinterpret_cast<f16x8*>(bfrag_hi)[off] = hi;
        reinterpret_cast<f16x8*>(bfrag_lo)[off] = lo;
    }
}

// ---------------- initial h ----------------
__global__ void k_hinit(const int* __restrict__ initial_ids,
                        const float* __restrict__ init_h,
                        const float* __restrict__ embed,
                        float* __restrict__ h_buf,
                        _Float16* __restrict__ hfrag_hi,
                        _Float16* __restrict__ hfrag_lo) {
    int row = blockIdx.x;
    int b = row >> 2;
    int t = threadIdx.x;
    int tok = initial_ids[b];
    for (int d = t; d < DD; d += 256) {
        float v = tanhf(init_h[b * DD + d] + embed[(size_t)tok * DD + d]);
        h_buf[row * DD + d] = v;
        pack_h(row, d, v, hfrag_hi, hfrag_lo);
    }
}

// ---------------- logits via MFMA fp16x2 split + fused per-block row-reduce ---------
// grid 500, block 256 (4 waves). Block: all 64 rows x 64 cols (4 col-tiles).
// Wave w: row-group w x all 4 col-tiles. A in regs; B staged NSLOT-deep in LDS.
// Epilogue: per-row top-8 + max/expsum over this block's 64 cols -> partials.
__global__ __launch_bounds__(256) void k_logits(
        const _Float16* __restrict__ bfrag_hi,
        const _Float16* __restrict__ bfrag_lo,
        const _Float16* __restrict__ hfrag_hi,
        const _Float16* __restrict__ hfrag_lo,
        float* __restrict__ ptv, int* __restrict__ pti,
        float* __restrict__ pm, float* __restrict__ ps) {
    int t = threadIdx.x;
    int w = t >> 6, l = t & 63;
    int ct0 = blockIdx.x * 4;
    int c0 = ct0 * 16;
    int colr = l & 15;
    int kg = l >> 4;
    int lq = l * 8;

    __shared__ _Float16 Bs[NSLOT][4][2][512];   // 48 KB; reused by epilogue

    // ---- A preload: this wave's row-group, 16 k-slices, hi+lo (128 VGPRs) ----
    f16x8 ah[16], al[16];
    #pragma unroll
    for (int ks = 0; ks < 16; ks++) {
        ah[ks] = *reinterpret_cast<const f16x8*>(hfrag_hi + ((w * 16 + ks) * 64 + l) * 8);
        al[ks] = *reinterpret_cast<const f16x8*>(hfrag_lo + ((w * 16 + ks) * 64 + l) * 8);
    }
    asm volatile("s_waitcnt vmcnt(0)" ::: "memory");   // clean vmcnt for counted waits
    __builtin_amdgcn_sched_barrier(0);

    f32x4 acc1[4], acc2[4];
    #pragma unroll
    for (int c2 = 0; c2 < 4; c2++) {
        acc1[c2] = (f32x4){0.f, 0.f, 0.f, 0.f};
        acc2[c2] = (f32x4){0.f, 0.f, 0.f, 0.f};
    }

    auto stage = [&](int s) {
        int slot = s % NSLOT;
        const _Float16* gh = bfrag_hi + (((size_t)(ct0 + w) * 16 + s) * 64 + l) * 8;
        const _Float16* gl = bfrag_lo + (((size_t)(ct0 + w) * 16 + s) * 64 + l) * 8;
        GLOAD_LDS16(gh, &Bs[slot][w][0][0]);
        GLOAD_LDS16(gl, &Bs[slot][w][1][0]);
    };

    stage(0); stage(1); stage(2); stage(3); stage(4); stage(5);

#define ITER(ks, NWAIT)                                                         \
    {                                                                           \
        asm volatile("s_waitcnt vmcnt(" #NWAIT ")" ::: "memory");               \
        __builtin_amdgcn_s_barrier();                                           \
        f16x8 bq[4][2];                                                         \
        _Pragma("unroll")                                                       \
        for (int c2 = 0; c2 < 4; c2++) {                                        \
            bq[c2][0] = *reinterpret_cast<const f16x8*>(&Bs[(ks) % NSLOT][c2][0][lq]); \
            bq[c2][1] = *reinterpret_cast<const f16x8*>(&Bs[(ks) % NSLOT][c2][1][lq]); \
        }                                                                       \
        asm volatile("s_waitcnt lgkmcnt(0)" ::: "memory");                      \
        __builtin_amdgcn_s_barrier();                                           \
        if ((ks) + NSLOT < 16) stage((ks) + NSLOT);                             \
        _Pragma("unroll")                                                       \
        for (int c2 = 0; c2 < 4; c2++) {                                        \
            acc1[c2] = __builtin_amdgcn_mfma_f32_16x16x32_f16(ah[(ks)], bq[c2][0], acc1[c2], 0, 0, 0); \
            acc2[c2] = __builtin_amdgcn_mfma_f32_16x16x32_f16(ah[(ks)], bq[c2][1], acc2[c2], 0, 0, 0); \
            acc2[c2] = __builtin_amdgcn_mfma_f32_16x16x32_f16(al[(ks)], bq[c2][0], acc2[c2], 0, 0, 0); \
        }                                                                       \
    }

    ITER(0, 10)  ITER(1, 10)  ITER(2, 10)  ITER(3, 10)
    ITER(4, 10)  ITER(5, 10)  ITER(6, 10)  ITER(7, 10)
    ITER(8, 10)  ITER(9, 10)  ITER(10, 10) ITER(11, 8)
    ITER(12, 6)  ITER(13, 4)  ITER(14, 2)  ITER(15, 0)
#undef ITER

    // ---- fused row-reduce epilogue (Bs is dead; reuse as scratch pool) ----
    char* pool = (char*)&Bs[0][0][0][0];
    float* Cs  = (float*)pool;               // [64][65] = 16640 B
    float* sv  = (float*)(pool + 16640);     // [256][8]
    int*   si  = (int*)  (pool + 24832);     // [256][8]
    float* smx = (float*)(pool + 33024);     // [256]
    float* ssm = (float*)(pool + 34048);     // [256]

    // C layout: col = lane&15, row = (lane>>4)*4 + reg
    #pragma unroll
    for (int c2 = 0; c2 < 4; c2++)
        #pragma unroll
        for (int j = 0; j < 4; j++)
            Cs[(w * 16 + kg * 4 + j) * 65 + c2 * 16 + colr] =
                acc1[c2][j] + acc2[c2][j] * (1.0f / SPLIT_S);
    __syncthreads();

    int row = t >> 2, cg = t & 3;
    float lv[8]; int li[8];
    #pragma unroll
    for (int j = 0; j < 8; j++) { lv[j] = -INFINITY; li[j] = 0x7fffffff; }
    float m = -INFINITY, s = 0.0f;
    #pragma unroll
    for (int cc = 0; cc < 16; cc++) {
        float v = Cs[row * 65 + cg * 16 + cc];
        int idx = c0 + cg * 16 + cc;
        float M = fmaxf(m, v);
        s = s * expf(m - M) + expf(v - M);
        m = M;
        INS8(v, idx, lv, li)
    }
    #pragma unroll
    for (int j = 0; j < 8; j++) { sv[t * 8 + j] = lv[j]; si[t * 8 + j] = li[j]; }
    smx[t] = m; ssm[t] = s;
    __syncthreads();
    for (int st = 2; st > 0; st >>= 1) {
        if ((t & 3) < st) {
            float rv[8]; int ri[8];
            int pa = 0, pb = 0;
            #pragma unroll
            for (int j = 0; j < 8; j++) {
                bool aok = pa < 8, bok = pb < 8;
                float va = sv[t * 8 + (aok ? pa : 7)], vb = sv[(t + st) * 8 + (bok ? pb : 7)];
                int   ia = si[t * 8 + (aok ? pa : 7)], ib = si[(t + st) * 8 + (bok ? pb : 7)];
                bool takeA = !bok || (aok && ((va > vb) || (va == vb && ia <= ib)));
                if (takeA) { rv[j] = va; ri[j] = ia; pa++; }
                else       { rv[j] = vb; ri[j] = ib; pb++; }
            }
            #pragma unroll
            for (int j = 0; j < 8; j++) { sv[t * 8 + j] = rv[j]; si[t * 8 + j] = ri[j]; }
            float ma = smx[t], mb = smx[t + st];
            float M = fmaxf(ma, mb);
            ssm[t] = ssm[t] * expf(ma - M) + ssm[t + st] * expf(mb - M);
            smx[t] = M;
        }
        __syncthreads();
    }
    if ((t & 3) == 0) {
        size_t base = ((size_t)row * NBLK + blockIdx.x) * 8;
        #pragma unroll
        for (int j = 0; j < 8; j++) { ptv[base + j] = sv[t * 8 + j]; pti[base + j] = si[t * 8 + j]; }
        pm[(size_t)row * NBLK + blockIdx.x] = smx[t];
        ps[(size_t)row * NBLK + blockIdx.x] = ssm[t];
    }
}

// ---------------- merge 500 block-partials per row -> top-8 + lse ----------------
// grid NROW, block 256
__global__ __launch_bounds__(256) void k_merge(
        const float* __restrict__ ptv, const int* __restrict__ pti,
        const float* __restrict__ pm, const float* __restrict__ ps,
        float* __restrict__ rowtop_val, int* __restrict__ rowtop_idx,
        float* __restrict__ row_lse) {
    int row = blockIdx.x, t = threadIdx.x;
    __shared__ float sval[256][8]; __shared__ int sidx[256][8];
    __shared__ float sm[256], ss[256];
    const float* pv = ptv + (size_t)row * NBLK * 8;
    const int*   pi = pti + (size_t)row * NBLK * 8;

    #pragma unroll
    for (int j = 0; j < 8; j++) { sval[t][j] = pv[t * 8 + j]; sidx[t][j] = pi[t * 8 + j]; }
    float m = pm[(size_t)row * NBLK + t], s = ps[(size_t)row * NBLK + t];
    if (t + 256 < NBLK) {
        const float* bv = pv + (size_t)(t + 256) * 8;
        const int*   bi = pi + (size_t)(t + 256) * 8;
        float rv[8]; int ri[8];
        int pa = 0, pb = 0;
        #pragma unroll
        for (int j = 0; j < 8; j++) {
            bool aok = pa < 8, bok = pb < 8;
            float va = sval[t][aok ? pa : 7], vb = bv[bok ? pb : 7];
            int   ia = sidx[t][aok ? pa : 7], ib = bi[bok ? pb : 7];
            bool takeA = !bok || (aok && ((va > vb) || (va == vb && ia <= ib)));
            if (takeA) { rv[j] = va; ri[j] = ia; pa++; }
            else       { rv[j] = vb; ri[j] = ib; pb++; }
        }
        #pragma unroll
        for (int j = 0; j < 8; j++) { sval[t][j] = rv[j]; sidx[t][j] = ri[j]; }
        float mb = pm[(size_t)row * NBLK + t + 256], sb = ps[(size_t)row * NBLK + t + 256];
        float M = fmaxf(m, mb);
        s = s * expf(m - M) + sb * expf(mb - M);
        m = M;
    }
    sm[t] = m; ss[t] = s;
    __syncthreads();
    for (int st = 128; st > 0; st >>= 1) {
        if (t < st) {
            float rv[8]; int ri[8];
            int pa = 0, pb = 0;
            #pragma unroll
            for (int j = 0; j < 8; j++) {
                bool aok = pa < 8, bok = pb < 8;
                float va = sval[t][aok ? pa : 7], vb = sval[t + st][bok ? pb : 7];
                int   ia = sidx[t][aok ? pa : 7], ib = sidx[t + st][bok ? pb : 7];
                bool takeA = !bok || (aok && ((va > vb) || (va == vb && ia <= ib)));
                if (takeA) { rv[j] = va; ri[j] = ia; pa++; }
                else       { rv[j] = vb; ri[j] = ib; pb++; }
            }
            #pragma unroll
            for (int j = 0; j < 8; j++) { sval[t][j] = rv[j]; sidx[t][j] = ri[j]; }
            float ma = sm[t], mb = sm[t + st];
            float M = fmaxf(ma, mb);
            ss[t] = ss[t] * expf(ma - M) + ss[t + st] * expf(mb - M);
            sm[t] = M;
        }
        __syncthreads();
    }
    if (t == 0) {
        #pragma unroll
        for (int j = 0; j < 8; j++) {
            rowtop_val[row * 8 + j] = sval[0][j];
            rowtop_idx[row * 8 + j] = sidx[0][j];
        }
        row_lse[row] = sm[0] + logf(ss[0]);
    }
}

// ---------------- beam update: parallel rank-based selection ----------------
// grid BB, block 256
__global__ __launch_bounds__(256) void k_update(
        const float* __restrict__ embed,
        float* h_buf, int* alive_seq, float* alive_lp,
        int* fin_seq, float* fin_sc, int* fin_fl,
        const float* __restrict__ rowtop_val, const int* __restrict__ rowtop_idx,
        const float* __restrict__ row_lse,
        _Float16* __restrict__ hfrag_hi, _Float16* __restrict__ hfrag_lo,
        int step) {
    int b = blockIdx.x;
    int t = threadIdx.x;
    __shared__ float h_old[KK][DD];
    __shared__ int old_aseq[KK][LL + 1], old_fseq[KK][LL + 1];
    __shared__ float lse_s[KK], alp_s[KK];
    __shared__ float clp[32]; __shared__ int cidx[32];
    __shared__ float c_lp[8];  __shared__ int c_beam[8], c_id[8], c_fl[8];
    __shared__ float asc_s[8], comb_s[12]; __shared__ int combfl_s[12];
    __shared__ int sel_alive[KK], sel_fin[KK];
    __shared__ float n_alp[KK], n_fsc[KK]; __shared__ int n_ffl[KK];

    for (int idx = t; idx < KK * (LL + 1); idx += 256) {
        old_aseq[idx / (LL + 1)][idx % (LL + 1)] = alive_seq[b * KK * (LL + 1) + idx];
        old_fseq[idx / (LL + 1)][idx % (LL + 1)] = fin_seq[b * KK * (LL + 1) + idx];
    }
    for (int idx = t; idx < KK * DD; idx += 256)
        h_old[idx >> 9][idx & (DD - 1)] = h_buf[b * KK * DD + idx];
    if (t < KK) {
        int r = b * KK + t;
        lse_s[t] = row_lse[r];
        alp_s[t] = alive_lp[r];
    }
    __syncthreads();

    // 32 candidates = 4 rows x 8. lp = logit - lse + alive_lp.
    if (t < 32) {
        int row = t >> 3;
        int src = (b * KK + row) * 8 + (t & 7);
        clp[t] = rowtop_val[src] - lse_s[row] + alp_s[row];
        cidx[t] = rowtop_idx[src];
    }
    __syncthreads();
    if (t < 32) {   // stable rank (tie key = row*V + token) -> top-8
        int row = t >> 3;
        float mylp = clp[t];
        int mykey = row * VV + cidx[t];
        int cnt = 0;
        #pragma unroll
        for (int j = 0; j < 32; j++) {
            int kj = (j >> 3) * VV + cidx[j];
            cnt += (clp[j] > mylp) || (clp[j] == mylp && kj < mykey);
        }
        if (cnt < 8) {
            c_lp[cnt] = mylp; c_beam[cnt] = row; c_id[cnt] = cidx[t];
            c_fl[cnt] = (cidx[t] == EOS_ID) ? 1 : 0;
        }
    }
    __syncthreads();
    if (t < 8) asc_s[t] = c_lp[t] + (c_fl[t] ? -NEGINF : 0.0f);
    if (t >= 64 && t < 76) {
        int j2 = t - 64;
        if (j2 < 4) { comb_s[j2] = fin_sc[b * KK + j2]; combfl_s[j2] = fin_fl[b * KK + j2]; }
        else {
            int cc = j2 - 4;
            float ln = powf((6.0f + (float)step) / 6.0f, ALPHA_C);
            comb_s[j2] = c_lp[cc] / ln + (c_fl[cc] ? 0.0f : -NEGINF);
            combfl_s[j2] = c_fl[cc];
        }
    }
    __syncthreads();
    if (t < 8) {   // alive: stable top-4 (ties: lower position)
        float a = asc_s[t];
        int cnt = 0;
        #pragma unroll
        for (int j = 0; j < 8; j++) cnt += (asc_s[j] > a) || (asc_s[j] == a && j < t);
        if (cnt < KK) { sel_alive[cnt] = t; n_alp[cnt] = a; }
    }
    if (t >= 64 && t < 76) {  // finished: stable top-4 (ties: lower position)
        int j2 = t - 64;
        float cval = comb_s[j2];
        int cnt = 0;
        #pragma unroll
        for (int j = 0; j < 12; j++) cnt += (comb_s[j] > cval) || (comb_s[j] == cval && j < j2);
        if (cnt < KK) { sel_fin[cnt] = j2; n_fsc[cnt] = cval; n_ffl[cnt] = combfl_s[j2]; }
    }
    __syncthreads();

    for (int idx = t; idx < KK * (LL + 1); idx += 256) {
        int j = idx / (LL + 1), p = idx % (LL + 1);
        int cand = sel_alive[j], bm = c_beam[cand];
        alive_seq[b * KK * (LL + 1) + idx] = (p == step + 1) ? c_id[cand] : old_aseq[bm][p];
        int src = sel_fin[j];
        int fval;
        if (src < 4) fval = old_fseq[src][p];
        else {
            int c2 = src - 4, bm2 = c_beam[c2];
            fval = (p == step + 1) ? c_id[c2] : old_aseq[bm2][p];
        }
        fin_seq[b * KK * (LL + 1) + idx] = fval;
    }
    for (int idx = t; idx < KK * DD; idx += 256) {
        int j = idx >> 9, d = idx & (DD - 1);
        int cand = sel_alive[j], bm = c_beam[cand], tok = c_id[cand];
        float v = tanhf(h_old[bm][d] + embed[(size_t)tok * DD + d]);
        int r = b * KK + j;
        h_buf[(size_t)r * DD + d] = v;
        pack_h(r, d, v, hfrag_hi, hfrag_lo);
    }
    if (t < KK) {
        alive_lp[b * KK + t] = n_alp[t];
        fin_sc[b * KK + t] = n_fsc[t];
        fin_fl[b * KK + t] = n_ffl[t];
    }
}

// ---------------- finalize ----------------
__global__ void k_final(const int* __restrict__ alive_seq, const float* __restrict__ alive_lp,
                        const int* __restrict__ fin_seq, const float* __restrict__ fin_sc,
                        const int* __restrict__ fin_fl, float* __restrict__ out) {
    int b = blockIdx.x;
    int t = threadIdx.x;
    __shared__ int anyf;
    if (t == 0)
        anyf = fin_fl[b * KK] | fin_fl[b * KK + 1] | fin_fl[b * KK + 2] | fin_fl[b * KK + 3];
    __syncthreads();
    for (int idx = t; idx < KK * (LL + 1); idx += blockDim.x) {
        int src = anyf ? fin_seq[b * KK * (LL + 1) + idx] : alive_seq[b * KK * (LL + 1) + idx];
        out[b * KK * (LL + 1) + idx] = (float)src;
    }
    if (t < KK)
        out[BB * KK * (LL + 1) + b * KK + t] = anyf ? fin_sc[b * KK + t] : alive_lp[b * KK + t];
}

extern "C" void kernel_launch(void* const* d_in, const int* in_sizes, int n_in,
                              void* d_out, int out_size, void* d_ws, size_t ws_size,
                              hipStream_t stream) {
    const int* initial_ids = (const int*)d_in[0];
    const float* init_h = (const float*)d_in[1];
    const float* embed = (const float*)d_in[2];
    const float* proj = (const float*)d_in[3];
    float* out = (float*)d_out;

    char* ws = (char*)d_ws;
    size_t off = 0;
    auto alloc = [&](size_t bytes) -> void* {
        off = (off + 255) & ~(size_t)255;
        void* p = ws + off;
        off += bytes;
        return p;
    };
    int* alive_seq    = (int*)alloc((size_t)NROW * (LL + 1) * 4);
    int* fin_seq      = (int*)alloc((size_t)NROW * (LL + 1) * 4);
    float* alive_lp   = (float*)alloc((size_t)NROW * 4);
    float* fin_sc     = (float*)alloc((size_t)NROW * 4);
    int* fin_fl       = (int*)alloc((size_t)NROW * 4);
    float* h_buf      = (float*)alloc((size_t)NROW * DD * 4);
    float* ptv        = (float*)alloc((size_t)NROW * NBLK * 8 * 4);
    int* pti          = (int*)alloc((size_t)NROW * NBLK * 8 * 4);
    float* pm         = (float*)alloc((size_t)NROW * NBLK * 4);
    float* ps         = (float*)alloc((size_t)NROW * NBLK * 4);
    float* rowtop_val = (float*)alloc((size_t)NROW * 8 * 4);
    int* rowtop_idx   = (int*)alloc((size_t)NROW * 8 * 4);
    float* row_lse    = (float*)alloc((size_t)NROW * 4);
    _Float16* hfrag_hi = (_Float16*)alloc((size_t)NROW * DD * 2);
    _Float16* hfrag_lo = (_Float16*)alloc((size_t)NROW * DD * 2);
    _Float16* bfrag_hi = (_Float16*)alloc((size_t)VV * DD * 2);
    _Float16* bfrag_lo = (_Float16*)alloc((size_t)VV * DD * 2);

    k_init<<<16, 256, 0, stream>>>(initial_ids, alive_seq, alive_lp,
                                   fin_seq, fin_sc, fin_fl);
    k_bconv<<<2000, 256, 0, stream>>>(proj, bfrag_hi, bfrag_lo);
    k_hinit<<<NROW, 256, 0, stream>>>(initial_ids, init_h, embed, h_buf,
                                      hfrag_hi, hfrag_lo);
    for (int step = 0; step < LL; step++) {
        k_logits<<<NBLK, 256, 0, stream>>>(bfrag_hi, bfrag_lo, hfrag_hi, hfrag_lo,
                                           ptv, pti, pm, ps);
        k_merge<<<NROW, 256, 0, stream>>>(ptv, pti, pm, ps,
                                          rowtop_val, rowtop_idx, row_lse);
        k_update<<<BB, 256, 0, stream>>>(embed, h_buf, alive_seq, alive_lp,
                                         fin_seq, fin_sc, fin_fl,
                                         rowtop_val, rowtop_idx, row_lse,
                                         hfrag_hi, hfrag_lo, step);
    }
    k_final<<<BB, 64, 0, stream>>>(alive_seq, alive_lp, fin_seq, fin_sc, fin_fl, out);
}

// Round 10
// 1467.096 us; speedup vs baseline: 1.9903x; 1.0030x over previous
//
#include <hip/hip_runtime.h>
#include <math.h>

#define BB 16
#define KK 4
#define VV 32000
#define DD 512
#define LL 32
#define EOS_ID 2
#define NEGINF 1.0e7f
#define ALPHA_C 0.6f
#define NROW (BB * KK)        // 64
#define NBLK 500              // k_logits blocks, 64 cols each
#define NSLOT 8
#define SPLIT_S 2048.0f

typedef _Float16 f16x8 __attribute__((ext_vector_type(8)));
typedef float f32x4 __attribute__((ext_vector_type(4)));

#define GLOAD_LDS16(gp, lp) \
    __builtin_amdgcn_global_load_lds( \
        (const __attribute__((address_space(1))) void*)(gp), \
        (__attribute__((address_space(3))) void*)(lp), 16, 0, 0)

// branchless stable top-8 insert (strict >: earlier/lower index wins ties).
// all private indices compile-time -> stays in VGPRs (rule #20).
#define INS8(v, idx, lv, li)                                          \
    if ((v) > lv[7]) {                                                \
        bool c_[8];                                                   \
        _Pragma("unroll")                                             \
        for (int j_ = 0; j_ < 8; j_++) c_[j_] = (v) > lv[j_];         \
        _Pragma("unroll")                                             \
        for (int j_ = 7; j_ >= 1; j_--) {                             \
            lv[j_] = c_[j_] ? (c_[j_ - 1] ? lv[j_ - 1] : (v)) : lv[j_];   \
            li[j_] = c_[j_] ? (c_[j_ - 1] ? li[j_ - 1] : (idx)) : li[j_]; \
        }                                                             \
        if (c_[0]) { lv[0] = (v); li[0] = (idx); }                    \
    }

// pack h value (global row r, depth d) into MFMA A-fragment order (fp16 hi/lo split)
__device__ inline void pack_h(int r, int d, float v,
                              _Float16* __restrict__ hfrag_hi,
                              _Float16* __restrict__ hfrag_lo) {
    _Float16 hi = (_Float16)v;
    _Float16 lo = (_Float16)((v - (float)hi) * SPLIT_S);
    int rg = r >> 4;
    int ks = d >> 5;
    int lane = (r & 15) + 16 * ((d >> 3) & 3);
    int e = d & 7;
    int off = (((rg * 16 + ks) * 64) + lane) * 8 + e;
    hfrag_hi[off] = hi;
    hfrag_lo[off] = lo;
}

// ---------------- init: sequences / scores ----------------
__global__ void k_init(const int* __restrict__ initial_ids,
                       int* alive_seq, float* alive_lp,
                       int* fin_seq, float* fin_sc, int* fin_fl) {
    int tid = blockIdx.x * blockDim.x + threadIdx.x;
    int nthreads = gridDim.x * blockDim.x;
    const int SEQ = NROW * (LL + 1);
    for (int idx = tid; idx < SEQ; idx += nthreads) {
        int pos = idx % (LL + 1);
        int b = (idx / (LL + 1)) / KK;
        alive_seq[idx] = (pos == 0) ? initial_ids[b] : 0;
        fin_seq[idx] = 0;
    }
    for (int idx = tid; idx < NROW; idx += nthreads) {
        int k = idx % KK;
        alive_lp[idx] = (k == 0) ? 0.0f : -NEGINF;
        fin_sc[idx] = -NEGINF;
        fin_fl[idx] = 0;
    }
}

// ---------------- one-time: proj -> fp16 hi/lo B-fragments ----------------
__global__ __launch_bounds__(256) void k_bconv(const float* __restrict__ proj,
                                               _Float16* __restrict__ bfrag_hi,
                                               _Float16* __restrict__ bfrag_lo) {
    int ct = blockIdx.x;
    int t = threadIdx.x;
    int w = t >> 6, l = t & 63;
    int col = ct * 16 + (l & 15);
    int kg = l >> 4;
    for (int ks = w; ks < 16; ks += 4) {
        int k0 = ks * 32 + kg * 8;
        f16x8 hi, lo;
        #pragma unroll
        for (int j = 0; j < 8; j++) {
            float v = proj[(size_t)(k0 + j) * VV + col];
            _Float16 h = (_Float16)v;
            hi[j] = h;
            lo[j] = (_Float16)((v - (float)h) * SPLIT_S);
        }
        size_t off = (size_t)(ct * 16 + ks) * 64 + l;
        reinterpret_cast<f16x8*>(bfrag_hi)[off] = hi;
        reinterpret_cast<f16x8*>(bfrag_lo)[off] = lo;
    }
}

// ---------------- initial h ----------------
__global__ void k_hinit(const int* __restrict__ initial_ids,
                        const float* __restrict__ init_h,
                        const float* __restrict__ embed,
                        float* __restrict__ h_buf,
                        _Float16* __restrict__ hfrag_hi,
                        _Float16* __restrict__ hfrag_lo) {
    int row = blockIdx.x;
    int b = row >> 2;
    int t = threadIdx.x;
    int tok = initial_ids[b];
    for (int d = t; d < DD; d += 256) {
        float v = tanhf(init_h[b * DD + d] + embed[(size_t)tok * DD + d]);
        h_buf[row * DD + d] = v;
        pack_h(row, d, v, hfrag_hi, hfrag_lo);
    }
}

// ---------------- logits via MFMA fp16x2 split + fused per-block row-reduce ---------
// grid 500, block 256 (4 waves). Block: all 64 rows x 64 cols (4 col-tiles).
// Wave w: row-group w x all 4 col-tiles. A in regs; B staged 8-deep in LDS.
// Single barrier per iter: at iter ks, each wave's lgkmcnt(0) in iter ks-1 ensures
// its slot-(ks-1) reads finished before this barrier, so stage(ks+7) (overwriting
// slot (ks-1)&7) is safe right after it. Per-wave vmcnt before the barrier
// publishes that wave's staged tile to the other 3 waves.
__global__ __launch_bounds__(256) void k_logits(
        const _Float16* __restrict__ bfrag_hi,
        const _Float16* __restrict__ bfrag_lo,
        const _Float16* __restrict__ hfrag_hi,
        const _Float16* __restrict__ hfrag_lo,
        float* __restrict__ ptv, int* __restrict__ pti,
        float* __restrict__ pm, float* __restrict__ ps) {
    int t = threadIdx.x;
    int w = t >> 6, l = t & 63;
    int ct0 = blockIdx.x * 4;
    int c0 = ct0 * 16;
    int colr = l & 15;
    int kg = l >> 4;
    int lq = l * 8;

    __shared__ _Float16 Bs[NSLOT][4][2][512];   // 64 KB; reused by epilogue

    // ---- A preload: this wave's row-group, 16 k-slices, hi+lo (128 VGPRs) ----
    f16x8 ah[16], al[16];
    #pragma unroll
    for (int ks = 0; ks < 16; ks++) {
        ah[ks] = *reinterpret_cast<const f16x8*>(hfrag_hi + ((w * 16 + ks) * 64 + l) * 8);
        al[ks] = *reinterpret_cast<const f16x8*>(hfrag_lo + ((w * 16 + ks) * 64 + l) * 8);
    }
    asm volatile("s_waitcnt vmcnt(0)" ::: "memory");   // clean vmcnt for counted waits
    __builtin_amdgcn_sched_barrier(0);

    f32x4 acc1[4], acc2[4];
    #pragma unroll
    for (int c2 = 0; c2 < 4; c2++) {
        acc1[c2] = (f32x4){0.f, 0.f, 0.f, 0.f};
        acc2[c2] = (f32x4){0.f, 0.f, 0.f, 0.f};
    }

    auto stage = [&](int s) {
        int slot = s & 7;
        const _Float16* gh = bfrag_hi + (((size_t)(ct0 + w) * 16 + s) * 64 + l) * 8;
        const _Float16* gl = bfrag_lo + (((size_t)(ct0 + w) * 16 + s) * 64 + l) * 8;
        GLOAD_LDS16(gh, &Bs[slot][w][0][0]);
        GLOAD_LDS16(gl, &Bs[slot][w][1][0]);
    };

    // prologue: 7 slots in flight (14 loads/wave)
    stage(0); stage(1); stage(2); stage(3); stage(4); stage(5); stage(6);

#define ITER(ks, NWAIT)                                                         \
    {                                                                           \
        asm volatile("s_waitcnt vmcnt(" #NWAIT ")" ::: "memory");               \
        __builtin_amdgcn_s_barrier();                                           \
        if ((ks) + 7 < 16) stage((ks) + 7);                                     \
        f16x8 bq[4][2];                                                         \
        _Pragma("unroll")                                                       \
        for (int c2 = 0; c2 < 4; c2++) {                                        \
            bq[c2][0] = *reinterpret_cast<const f16x8*>(&Bs[(ks) & 7][c2][0][lq]); \
            bq[c2][1] = *reinterpret_cast<const f16x8*>(&Bs[(ks) & 7][c2][1][lq]); \
        }                                                                       \
        asm volatile("s_waitcnt lgkmcnt(0)" ::: "memory");                      \
        _Pragma("unroll")                                                       \
        for (int c2 = 0; c2 < 4; c2++) {                                        \
            acc1[c2] = __builtin_amdgcn_mfma_f32_16x16x32_f16(ah[(ks)], bq[c2][0], acc1[c2], 0, 0, 0); \
            acc2[c2] = __builtin_amdgcn_mfma_f32_16x16x32_f16(ah[(ks)], bq[c2][1], acc2[c2], 0, 0, 0); \
            acc2[c2] = __builtin_amdgcn_mfma_f32_16x16x32_f16(al[(ks)], bq[c2][0], acc2[c2], 0, 0, 0); \
        }                                                                       \
    }

    ITER(0, 12)  ITER(1, 12)  ITER(2, 12)  ITER(3, 12)
    ITER(4, 12)  ITER(5, 12)  ITER(6, 12)  ITER(7, 12)
    ITER(8, 12)  ITER(9, 12)  ITER(10, 10) ITER(11, 8)
    ITER(12, 6)  ITER(13, 4)  ITER(14, 2)  ITER(15, 0)
#undef ITER

    // ---- fused row-reduce epilogue (Bs is dead; reuse as scratch pool) ----
    char* pool = (char*)&Bs[0][0][0][0];
    float* Cs  = (float*)pool;               // [64][65] = 16640 B
    float* sv  = (float*)(pool + 16640);     // [256][8]
    int*   si  = (int*)  (pool + 24832);     // [256][8]
    float* smx = (float*)(pool + 33024);     // [256]
    float* ssm = (float*)(pool + 34048);     // [256]

    // C layout: col = lane&15, row = (lane>>4)*4 + reg
    #pragma unroll
    for (int c2 = 0; c2 < 4; c2++)
        #pragma unroll
        for (int j = 0; j < 4; j++)
            Cs[(w * 16 + kg * 4 + j) * 65 + c2 * 16 + colr] =
                acc1[c2][j] + acc2[c2][j] * (1.0f / SPLIT_S);
    __syncthreads();

    int row = t >> 2, cg = t & 3;
    float lv[8]; int li[8];
    #pragma unroll
    for (int j = 0; j < 8; j++) { lv[j] = -INFINITY; li[j] = 0x7fffffff; }
    float m = -INFINITY, s = 0.0f;
    #pragma unroll
    for (int cc = 0; cc < 16; cc++) {
        float v = Cs[row * 65 + cg * 16 + cc];
        int idx = c0 + cg * 16 + cc;
        float M = fmaxf(m, v);
        s = s * expf(m - M) + expf(v - M);
        m = M;
        INS8(v, idx, lv, li)
    }
    #pragma unroll
    for (int j = 0; j < 8; j++) { sv[t * 8 + j] = lv[j]; si[t * 8 + j] = li[j]; }
    smx[t] = m; ssm[t] = s;
    __syncthreads();
    for (int st = 2; st > 0; st >>= 1) {
        if ((t & 3) < st) {
            float rv[8]; int ri[8];
            int pa = 0, pb = 0;
            #pragma unroll
            for (int j = 0; j < 8; j++) {
                bool aok = pa < 8, bok = pb < 8;
                float va = sv[t * 8 + (aok ? pa : 7)], vb = sv[(t + st) * 8 + (bok ? pb : 7)];
                int   ia = si[t * 8 + (aok ? pa : 7)], ib = si[(t + st) * 8 + (bok ? pb : 7)];
                bool takeA = !bok || (aok && ((va > vb) || (va == vb && ia <= ib)));
                if (takeA) { rv[j] = va; ri[j] = ia; pa++; }
                else       { rv[j] = vb; ri[j] = ib; pb++; }
            }
            #pragma unroll
            for (int j = 0; j < 8; j++) { sv[t * 8 + j] = rv[j]; si[t * 8 + j] = ri[j]; }
            float ma = smx[t], mb = smx[t + st];
            float M = fmaxf(ma, mb);
            ssm[t] = ssm[t] * expf(ma - M) + ssm[t + st] * expf(mb - M);
            smx[t] = M;
        }
        __syncthreads();
    }
    if ((t & 3) == 0) {
        size_t base = ((size_t)row * NBLK + blockIdx.x) * 8;
        #pragma unroll
        for (int j = 0; j < 8; j++) { ptv[base + j] = sv[t * 8 + j]; pti[base + j] = si[t * 8 + j]; }
        pm[(size_t)row * NBLK + blockIdx.x] = smx[t];
        ps[(size_t)row * NBLK + blockIdx.x] = ssm[t];
    }
}

// ---------------- merge 500 block-partials per row -> top-8 + lse ----------------
// grid NROW, block 256
__global__ __launch_bounds__(256) void k_merge(
        const float* __restrict__ ptv, const int* __restrict__ pti,
        const float* __restrict__ pm, const float* __restrict__ ps,
        float* __restrict__ rowtop_val, int* __restrict__ rowtop_idx,
        float* __restrict__ row_lse) {
    int row = blockIdx.x, t = threadIdx.x;
    __shared__ float sval[256][8]; __shared__ int sidx[256][8];
    __shared__ float sm[256], ss[256];
    const float* pv = ptv + (size_t)row * NBLK * 8;
    const int*   pi = pti + (size_t)row * NBLK * 8;

    #pragma unroll
    for (int j = 0; j < 8; j++) { sval[t][j] = pv[t * 8 + j]; sidx[t][j] = pi[t * 8 + j]; }
    float m = pm[(size_t)row * NBLK + t], s = ps[(size_t)row * NBLK + t];
    if (t + 256 < NBLK) {
        const float* bv = pv + (size_t)(t + 256) * 8;
        const int*   bi = pi + (size_t)(t + 256) * 8;
        float rv[8]; int ri[8];
        int pa = 0, pb = 0;
        #pragma unroll
        for (int j = 0; j < 8; j++) {
            bool aok = pa < 8, bok = pb < 8;
            float va = sval[t][aok ? pa : 7], vb = bv[bok ? pb : 7];
            int   ia = sidx[t][aok ? pa : 7], ib = bi[bok ? pb : 7];
            bool takeA = !bok || (aok && ((va > vb) || (va == vb && ia <= ib)));
            if (takeA) { rv[j] = va; ri[j] = ia; pa++; }
            else       { rv[j] = vb; ri[j] = ib; pb++; }
        }
        #pragma unroll
        for (int j = 0; j < 8; j++) { sval[t][j] = rv[j]; sidx[t][j] = ri[j]; }
        float mb = pm[(size_t)row * NBLK + t + 256], sb = ps[(size_t)row * NBLK + t + 256];
        float M = fmaxf(m, mb);
        s = s * expf(m - M) + sb * expf(mb - M);
        m = M;
    }
    sm[t] = m; ss[t] = s;
    __syncthreads();
    for (int st = 128; st > 0; st >>= 1) {
        if (t < st) {
            float rv[8]; int ri[8];
            int pa = 0, pb = 0;
            #pragma unroll
            for (int j = 0; j < 8; j++) {
                bool aok = pa < 8, bok = pb < 8;
                float va = sval[t][aok ? pa : 7], vb = sval[t + st][bok ? pb : 7];
                int   ia = sidx[t][aok ? pa : 7], ib = sidx[t + st][bok ? pb : 7];
                bool takeA = !bok || (aok && ((va > vb) || (va == vb && ia <= ib)));
                if (takeA) { rv[j] = va; ri[j] = ia; pa++; }
                else       { rv[j] = vb; ri[j] = ib; pb++; }
            }
            #pragma unroll
            for (int j = 0; j < 8; j++) { sval[t][j] = rv[j]; sidx[t][j] = ri[j]; }
            float ma = sm[t], mb = sm[t + st];
            float M = fmaxf(ma, mb);
            ss[t] = ss[t] * expf(ma - M) + ss[t + st] * expf(mb - M);
            sm[t] = M;
        }
        __syncthreads();
    }
    if (t == 0) {
        #pragma unroll
        for (int j = 0; j < 8; j++) {
            rowtop_val[row * 8 + j] = sval[0][j];
            rowtop_idx[row * 8 + j] = sidx[0][j];
        }
        row_lse[row] = sm[0] + logf(ss[0]);
    }
}

// ---------------- beam update: parallel rank-based selection ----------------
// grid BB, block 256
__global__ __launch_bounds__(256) void k_update(
        const float* __restrict__ embed,
        float* h_buf, int* alive_seq, float* alive_lp,
        int* fin_seq, float* fin_sc, int* fin_fl,
        const float* __restrict__ rowtop_val, const int* __restrict__ rowtop_idx,
        const float* __restrict__ row_lse,
        _Float16* __restrict__ hfrag_hi, _Float16* __restrict__ hfrag_lo,
        int step) {
    int b = blockIdx.x;
    int t = threadIdx.x;
    __shared__ float h_old[KK][DD];
    __shared__ int old_aseq[KK][LL + 1], old_fseq[KK][LL + 1];
    __shared__ float lse_s[KK], alp_s[KK];
    __shared__ float clp[32]; __shared__ int cidx[32];
    __shared__ float c_lp[8];  __shared__ int c_beam[8], c_id[8], c_fl[8];
    __shared__ float asc_s[8], comb_s[12]; __shared__ int combfl_s[12];
    __shared__ int sel_alive[KK], sel_fin[KK];
    __shared__ float n_alp[KK], n_fsc[KK]; __shared__ int n_ffl[KK];

    for (int idx = t; idx < KK * (LL + 1); idx += 256) {
        old_aseq[idx / (LL + 1)][idx % (LL + 1)] = alive_seq[b * KK * (LL + 1) + idx];
        old_fseq[idx / (LL + 1)][idx % (LL + 1)] = fin_seq[b * KK * (LL + 1) + idx];
    }
    for (int idx = t; idx < KK * DD; idx += 256)
        h_old[idx >> 9][idx & (DD - 1)] = h_buf[b * KK * DD + idx];
    if (t < KK) {
        int r = b * KK + t;
        lse_s[t] = row_lse[r];
        alp_s[t] = alive_lp[r];
    }
    __syncthreads();

    // 32 candidates = 4 rows x 8. lp = logit - lse + alive_lp.
    if (t < 32) {
        int row = t >> 3;
        int src = (b * KK + row) * 8 + (t & 7);
        clp[t] = rowtop_val[src] - lse_s[row] + alp_s[row];
        cidx[t] = rowtop_idx[src];
    }
    __syncthreads();
    if (t < 32) {   // stable rank (tie key = row*V + token) -> top-8
        int row = t >> 3;
        float mylp = clp[t];
        int mykey = row * VV + cidx[t];
        int cnt = 0;
        #pragma unroll
        for (int j = 0; j < 32; j++) {
            int kj = (j >> 3) * VV + cidx[j];
            cnt += (clp[j] > mylp) || (clp[j] == mylp && kj < mykey);
        }
        if (cnt < 8) {
            c_lp[cnt] = mylp; c_beam[cnt] = row; c_id[cnt] = cidx[t];
            c_fl[cnt] = (cidx[t] == EOS_ID) ? 1 : 0;
        }
    }
    __syncthreads();
    if (t < 8) asc_s[t] = c_lp[t] + (c_fl[t] ? -NEGINF : 0.0f);
    if (t >= 64 && t < 76) {
        int j2 = t - 64;
        if (j2 < 4) { comb_s[j2] = fin_sc[b * KK + j2]; combfl_s[j2] = fin_fl[b * KK + j2]; }
        else {
            int cc = j2 - 4;
            float ln = powf((6.0f + (float)step) / 6.0f, ALPHA_C);
            comb_s[j2] = c_lp[cc] / ln + (c_fl[cc] ? 0.0f : -NEGINF);
            combfl_s[j2] = c_fl[cc];
        }
    }
    __syncthreads();
    if (t < 8) {   // alive: stable top-4 (ties: lower position)
        float a = asc_s[t];
        int cnt = 0;
        #pragma unroll
        for (int j = 0; j < 8; j++) cnt += (asc_s[j] > a) || (asc_s[j] == a && j < t);
        if (cnt < KK) { sel_alive[cnt] = t; n_alp[cnt] = a; }
    }
    if (t >= 64 && t < 76) {  // finished: stable top-4 (ties: lower position)
        int j2 = t - 64;
        float cval = comb_s[j2];
        int cnt = 0;
        #pragma unroll
        for (int j = 0; j < 12; j++) cnt += (comb_s[j] > cval) || (comb_s[j] == cval && j < j2);
        if (cnt < KK) { sel_fin[cnt] = j2; n_fsc[cnt] = cval; n_ffl[cnt] = combfl_s[j2]; }
    }
    __syncthreads();

    for (int idx = t; idx < KK * (LL + 1); idx += 256) {
        int j = idx / (LL + 1), p = idx % (LL + 1);
        int cand = sel_alive[j], bm = c_beam[cand];
        alive_seq[b * KK * (LL + 1) + idx] = (p == step + 1) ? c_id[cand] : old_aseq[bm][p];
        int src = sel_fin[j];
        int fval;
        if (src < 4) fval = old_fseq[src][p];
        else {
            int c2 = src - 4, bm2 = c_beam[c2];
            fval = (p == step + 1) ? c_id[c2] : old_aseq[bm2][p];
        }
        fin_seq[b * KK * (LL + 1) + idx] = fval;
    }
    for (int idx = t; idx < KK * DD; idx += 256) {
        int j = idx >> 9, d = idx & (DD - 1);
        int cand = sel_alive[j], bm = c_beam[cand], tok = c_id[cand];
        float v = tanhf(h_old[bm][d] + embed[(size_t)tok * DD + d]);
        int r = b * KK + j;
        h_buf[(size_t)r * DD + d] = v;
        pack_h(r, d, v, hfrag_hi, hfrag_lo);
    }
    if (t < KK) {
        alive_lp[b * KK + t] = n_alp[t];
        fin_sc[b * KK + t] = n_fsc[t];
        fin_fl[b * KK + t] = n_ffl[t];
    }
}

// ---------------- finalize ----------------
__global__ void k_final(const int* __restrict__ alive_seq, const float* __restrict__ alive_lp,
                        const int* __restrict__ fin_seq, const float* __restrict__ fin_sc,
                        const int* __restrict__ fin_fl, float* __restrict__ out) {
    int b = blockIdx.x;
    int t = threadIdx.x;
    __shared__ int anyf;
    if (t == 0)
        anyf = fin_fl[b * KK] | fin_fl[b * KK + 1] | fin_fl[b * KK + 2] | fin_fl[b * KK + 3];
    __syncthreads();
    for (int idx = t; idx < KK * (LL + 1); idx += blockDim.x) {
        int src = anyf ? fin_seq[b * KK * (LL + 1) + idx] : alive_seq[b * KK * (LL + 1) + idx];
        out[b * KK * (LL + 1) + idx] = (float)src;
    }
    if (t < KK)
        out[BB * KK * (LL + 1) + b * KK + t] = anyf ? fin_sc[b * KK + t] : alive_lp[b * KK + t];
}

extern "C" void kernel_launch(void* const* d_in, const int* in_sizes, int n_in,
                              void* d_out, int out_size, void* d_ws, size_t ws_size,
                              hipStream_t stream) {
    const int* initial_ids = (const int*)d_in[0];
    const float* init_h = (const float*)d_in[1];
    const float* embed = (const float*)d_in[2];
    const float* proj = (const float*)d_in[3];
    float* out = (float*)d_out;

    char* ws = (char*)d_ws;
    size_t off = 0;
    auto alloc = [&](size_t bytes) -> void* {
        off = (off + 255) & ~(size_t)255;
        void* p = ws + off;
        off += bytes;
        return p;
    };
    int* alive_seq    = (int*)alloc((size_t)NROW * (LL + 1) * 4);
    int* fin_seq      = (int*)alloc((size_t)NROW * (LL + 1) * 4);
    float* alive_lp   = (float*)alloc((size_t)NROW * 4);
    float* fin_sc     = (float*)alloc((size_t)NROW * 4);
    int* fin_fl       = (int*)alloc((size_t)NROW * 4);
    float* h_buf      = (float*)alloc((size_t)NROW * DD * 4);
    float* ptv        = (float*)alloc((size_t)NROW * NBLK * 8 * 4);
    int* pti          = (int*)alloc((size_t)NROW * NBLK * 8 * 4);
    float* pm         = (float*)alloc((size_t)NROW * NBLK * 4);
    float* ps         = (float*)alloc((size_t)NROW * NBLK * 4);
    float* rowtop_val = (float*)alloc((size_t)NROW * 8 * 4);
    int* rowtop_idx   = (int*)alloc((size_t)NROW * 8 * 4);
    float* row_lse    = (float*)alloc((size_t)NROW * 4);
    _Float16* hfrag_hi = (_Float16*)alloc((size_t)NROW * DD * 2);
    _Float16* hfrag_lo = (_Float16*)alloc((size_t)NROW * DD * 2);
    _Float16* bfrag_hi = (_Float16*)alloc((size_t)VV * DD * 2);
    _Float16* bfrag_lo = (_Float16*)alloc((size_t)VV * DD * 2);

    k_init<<<16, 256, 0, stream>>>(initial_ids, alive_seq, alive_lp,
                                   fin_seq, fin_sc, fin_fl);
    k_bconv<<<2000, 256, 0, stream>>>(proj, bfrag_hi, bfrag_lo);
    k_hinit<<<NROW, 256, 0, stream>>>(initial_ids, init_h, embed, h_buf,
                                      hfrag_hi, hfrag_lo);
    for (int step = 0; step < LL; step++) {
        k_logits<<<NBLK, 256, 0, stream>>>(bfrag_hi, bfrag_lo, hfrag_hi, hfrag_lo,
                                           ptv, pti, pm, ps);
        k_merge<<<NROW, 256, 0, stream>>>(ptv, pti, pm, ps,
                                          rowtop_val, rowtop_idx, row_lse);
        k_update<<<BB, 256, 0, stream>>>(embed, h_buf, alive_seq, alive_lp,
                                         fin_seq, fin_sc, fin_fl,
                                         rowtop_val, rowtop_idx, row_lse,
                                         hfrag_hi, hfrag_lo, step);
    }
    k_final<<<BB, 64, 0, stream>>>(alive_seq, alive_lp, fin_seq, fin_sc, fin_fl, out);
}